// Round 2
// 542.286 us; speedup vs baseline: 1.0836x; 1.0836x over previous
//
#include <hip/hip_runtime.h>
#include <hip/hip_bf16.h>
#include <stdint.h>

// Problem constants (K=4, OUT=4096, IN=4096, B=2, S=2048)
#define DIM_M 4096   // B*S rows of x
#define DIM_N 4096   // OUT
#define DIM_K 4096   // IN
#define BASE_STRIDE (DIM_N * DIM_K)  // elements per basis
#define NT (DIM_K / 64)              // 64 K-tiles of BK=64

typedef __bf16 bf16x8 __attribute__((ext_vector_type(8)));
typedef float floatx16 __attribute__((ext_vector_type(16)));
typedef unsigned short ushort8 __attribute__((ext_vector_type(8)));

__device__ __forceinline__ unsigned short f2bf(float f) {
    uint32_t u = __float_as_uint(f);
    uint32_t r = (u + 0x7FFFu + ((u >> 16) & 1u)) >> 16;  // RNE
    return (unsigned short)r;
}

// ---------------------------------------------------------------------------
// Fused prologue (unchanged, verified): blocks [0,8192) build W_bf16;
// [8192,16384) convert x fp32 -> bf16. 8 elems/thread, 16B stores.
// ---------------------------------------------------------------------------
__global__ __launch_bounds__(256) void prep_kernel(
        const int* __restrict__ bases, const float* __restrict__ alphas,
        const float* __restrict__ x,
        unsigned short* __restrict__ Wb, unsigned short* __restrict__ Xb) {
    const int bid = blockIdx.x;
    if (bid < 8192) {
        const long e = ((long)bid * 256 + threadIdx.x) * 8;
        const float a0 = alphas[0], a1 = alphas[1], a2 = alphas[2], a3 = alphas[3];
        const int4 p0 = *(const int4*)(bases + e);
        const int4 p1 = *(const int4*)(bases + e + 4);
        const int4 q0 = *(const int4*)(bases + BASE_STRIDE + e);
        const int4 q1 = *(const int4*)(bases + BASE_STRIDE + e + 4);
        const int4 r0 = *(const int4*)(bases + 2L * BASE_STRIDE + e);
        const int4 r1 = *(const int4*)(bases + 2L * BASE_STRIDE + e + 4);
        const int4 s0 = *(const int4*)(bases + 3L * BASE_STRIDE + e);
        const int4 s1 = *(const int4*)(bases + 3L * BASE_STRIDE + e + 4);
        ushort8 o;
        o[0] = f2bf(a0 * p0.x + a1 * q0.x + a2 * r0.x + a3 * s0.x);
        o[1] = f2bf(a0 * p0.y + a1 * q0.y + a2 * r0.y + a3 * s0.y);
        o[2] = f2bf(a0 * p0.z + a1 * q0.z + a2 * r0.z + a3 * s0.z);
        o[3] = f2bf(a0 * p0.w + a1 * q0.w + a2 * r0.w + a3 * s0.w);
        o[4] = f2bf(a0 * p1.x + a1 * q1.x + a2 * r1.x + a3 * s1.x);
        o[5] = f2bf(a0 * p1.y + a1 * q1.y + a2 * r1.y + a3 * s1.y);
        o[6] = f2bf(a0 * p1.z + a1 * q1.z + a2 * r1.z + a3 * s1.z);
        o[7] = f2bf(a0 * p1.w + a1 * q1.w + a2 * r1.w + a3 * s1.w);
        *(ushort8*)(Wb + e) = o;
    } else {
        const long e = ((long)(bid - 8192) * 256 + threadIdx.x) * 8;
        const float4 v0 = *(const float4*)(x + e);
        const float4 v1 = *(const float4*)(x + e + 4);
        ushort8 o;
        o[0] = f2bf(v0.x); o[1] = f2bf(v0.y); o[2] = f2bf(v0.z); o[3] = f2bf(v0.w);
        o[4] = f2bf(v1.x); o[5] = f2bf(v1.y); o[6] = f2bf(v1.z); o[7] = f2bf(v1.w);
        *(ushort8*)(Xb + e) = o;
    }
}

// ---------------------------------------------------------------------------
// Main GEMM, 256x256 tile / BK=64 / 8-wave / 8-phase schedule (T2+T3+T4+T5).
//
// LDS: lds[buf][op A=0,B=1][half 0,1][128 rows x 64 cols bf16] = 128 KiB.
// Staged with global_load_lds width=16 (linear LDS dest = wave base + lane*16).
// Swizzle (T2): LDS(row, chunk) holds global chunk (chunk ^ (row&7)); applied
// by pre-swizzling the per-lane GLOBAL source address (write side) and
// XOR-ing the chunk on ds_read (read side). A wave64 ds_read_b128 of a
// column-slice then spreads to 8 words/bank = the bandwidth minimum.
//
// Schedule per K-tile t (4 phases), 2 tiles per loop iteration:
//   P1: dsr A(mi0,1)+B(nh0) [12 x b128]; stage A1(t+1)->other buf
//   P2: dsr B(nh1) [4]
//   P3: dsr A(mi2,3) [8];  stage B0(t+2)->this buf   (B reads ended at P2)
//   P4: stage B1(t+2), A0(t+2)->this buf (A reads ended at P3);
//       s_waitcnt vmcnt(6)  <- 3 half-tiles in flight, never drained to 0
// Each phase: [dsr; stage; s_barrier; setprio(1); 8x mfma_32x32x16; setprio(0);
// s_barrier].
//
// vmcnt ledger (verified by hand, steady state): enter iter with 6
// outstanding (tile 2i+1 B0,B1,A0); +2 (P1) +2 (P3) +4 (P4) = 14; vmcnt(6)
// retires the 8 oldest = exactly tile 2i+1 -> group B may read buf1.
// Symmetric for group B -> tile 2i+2 lands before next iter. Last iter
// drains with vmcnt(0). WAR: every LDS half is rewritten >=2 barriers after
// its last ds_read, whose data is register-consumed (compiler lgkmcnt)
// before the intervening barrier. The vmcnt asm's "memory" clobber pins
// ds_reads below the landing guarantee.
//
// 32x32x16 layouts (HW-verified prior session, absmax 4.0): A/B operand
// m(/n)=lane&31, k=(lane>>5)*8+j; C/D col=lane&31, row=(r&3)+8*(r>>2)+4*g32.
// ---------------------------------------------------------------------------
#define MFMA32 __builtin_amdgcn_mfma_f32_32x32x16_bf16
#define BAR()   __builtin_amdgcn_s_barrier()
#define PRIO1() __builtin_amdgcn_s_setprio(1)
#define PRIO0() __builtin_amdgcn_s_setprio(0)

__device__ __forceinline__ void stage_half(const unsigned short* __restrict__ gb,
        int grow0, int kbase, unsigned short* ld, int wave, int lane) {
#pragma unroll
    for (int r = 0; r < 2; ++r) {
        const int row = wave * 16 + r * 8 + (lane >> 3);       // local row in half
        const int ch  = (lane & 7) ^ (row & 7);                // pre-swizzled src chunk
        const unsigned short* g = gb + (size_t)(grow0 + row) * DIM_K + kbase + ch * 8;
        unsigned short* d = ld + (wave * 16 + r * 8) * 64;     // wave-uniform LDS base
        __builtin_amdgcn_global_load_lds(
            (const __attribute__((address_space(1))) unsigned int*)((const void*)g),
            (__attribute__((address_space(3))) unsigned int*)((void*)d), 16, 0, 0);
    }
}

#define DS_A(LD, MI, SLOT)                                                        \
    do { _Pragma("unroll") for (int k = 0; k < 4; ++k)                            \
        a[SLOT][k] = *(const bf16x8*)((LD) + ((MI) * 32 + l31) * 64 + cko[k]);    \
    } while (0)
#define DS_B(LD, NH, SLOT)                                                        \
    do { _Pragma("unroll") for (int k = 0; k < 4; ++k)                            \
        b[SLOT][k] = *(const bf16x8*)((LD) + (nloc + (NH) * 32 + l31) * 64 + cko[k]); \
    } while (0)
#define MM2(MI0, MI1, NH, SB)                                                     \
    do { _Pragma("unroll") for (int k = 0; k < 4; ++k) {                          \
        acc[MI0][NH] = MFMA32(a[0][k], b[SB][k], acc[MI0][NH], 0, 0, 0);          \
        acc[MI1][NH] = MFMA32(a[1][k], b[SB][k], acc[MI1][NH], 0, 0, 0);          \
    } } while (0)

__global__ __launch_bounds__(512, 2) void gemm_bt_kernel(
        const unsigned short* __restrict__ A, const unsigned short* __restrict__ Bt,
        float* __restrict__ C) {
    __shared__ __align__(16) unsigned short lds[2][2][2][128 * 64];  // 128 KiB

    const int t = threadIdx.x;
    const int wave = t >> 6, lane = t & 63;
    const int l31 = lane & 31, g32 = lane >> 5;
    const int wm = wave >> 2;            // 0..1  -> A half / row block of 128
    const int wn = wave & 3;             // 0..3  -> 64-col block
    const int nloc = (wn & 1) * 64;      // row offset inside B half (wn>>1)

    const int mBase = blockIdx.y * 256;
    const int nBase = blockIdx.x * 256;

    const unsigned short* LA0 = &lds[0][0][wm][0];
    const unsigned short* LA1 = &lds[1][0][wm][0];
    const unsigned short* LB0 = &lds[0][1][wn >> 1][0];
    const unsigned short* LB1 = &lds[1][1][wn >> 1][0];

    int cko[4];
#pragma unroll
    for (int k = 0; k < 4; ++k) cko[k] = ((k * 2 + g32) ^ (l31 & 7)) * 8;

    floatx16 acc[4][2] = {};
    bf16x8 a[2][4], b[2][4];

    // ---- prologue: tile0 -> buf0 (A0,A1,B0,B1); tile1 -> buf1 (B0,B1,A0) ----
    stage_half(A,  mBase + 0,   0,  &lds[0][0][0][0], wave, lane);
    stage_half(A,  mBase + 128, 0,  &lds[0][0][1][0], wave, lane);
    stage_half(Bt, nBase + 0,   0,  &lds[0][1][0][0], wave, lane);
    stage_half(Bt, nBase + 128, 0,  &lds[0][1][1][0], wave, lane);
    stage_half(Bt, nBase + 0,   64, &lds[1][1][0][0], wave, lane);
    stage_half(Bt, nBase + 128, 64, &lds[1][1][1][0], wave, lane);
    stage_half(A,  mBase + 0,   64, &lds[1][0][0][0], wave, lane);
    asm volatile("s_waitcnt vmcnt(6)" ::: "memory");   // tile0 fully landed
    BAR();

    for (int i = 0; i < NT / 2; ++i) {
        const bool more = (i < NT / 2 - 1);
        const int t1k = (2 * i + 1) * 64;
        const int t2k = (2 * i + 2) * 64;
        const int t3k = (2 * i + 3) * 64;

        // ================= group A: tile 2i from buf0 =================
        // P1
        DS_A(LA0, 0, 0); DS_A(LA0, 1, 1); DS_B(LB0, 0, 0);
        stage_half(A, mBase + 128, t1k, &lds[1][0][1][0], wave, lane);   // A1(t+1)
        BAR(); PRIO1(); MM2(0, 1, 0, 0); PRIO0(); BAR();
        // P2
        DS_B(LB0, 1, 1);
        BAR(); PRIO1(); MM2(0, 1, 1, 1); PRIO0(); BAR();
        // P3
        DS_A(LA0, 2, 0); DS_A(LA0, 3, 1);
        if (more) stage_half(Bt, nBase + 0, t2k, &lds[0][1][0][0], wave, lane);
        BAR(); PRIO1(); MM2(2, 3, 1, 1); PRIO0(); BAR();
        // P4
        if (more) {
            stage_half(Bt, nBase + 128, t2k, &lds[0][1][1][0], wave, lane);
            stage_half(A,  mBase + 0,   t2k, &lds[0][0][0][0], wave, lane);
            asm volatile("s_waitcnt vmcnt(6)" ::: "memory");
        } else {
            asm volatile("s_waitcnt vmcnt(0)" ::: "memory");
        }
        BAR(); PRIO1(); MM2(2, 3, 0, 0); PRIO0(); BAR();

        // ================= group B: tile 2i+1 from buf1 =================
        // P1
        DS_A(LA1, 0, 0); DS_A(LA1, 1, 1); DS_B(LB1, 0, 0);
        if (more) stage_half(A, mBase + 128, t2k, &lds[0][0][1][0], wave, lane); // A1(t+2)
        BAR(); PRIO1(); MM2(0, 1, 0, 0); PRIO0(); BAR();
        // P2
        DS_B(LB1, 1, 1);
        BAR(); PRIO1(); MM2(0, 1, 1, 1); PRIO0(); BAR();
        // P3
        DS_A(LA1, 2, 0); DS_A(LA1, 3, 1);
        if (more) stage_half(Bt, nBase + 0, t3k, &lds[1][1][0][0], wave, lane);
        BAR(); PRIO1(); MM2(2, 3, 1, 1); PRIO0(); BAR();
        // P4
        if (more) {
            stage_half(Bt, nBase + 128, t3k, &lds[1][1][1][0], wave, lane);
            stage_half(A,  mBase + 0,   t3k, &lds[1][0][0][0], wave, lane);
            asm volatile("s_waitcnt vmcnt(6)" ::: "memory");
        } else {
            asm volatile("s_waitcnt vmcnt(0)" ::: "memory");
        }
        BAR(); PRIO1(); MM2(2, 3, 0, 0); PRIO0(); BAR();
    }

    // Epilogue: C/D layout col=lane&31, row=(r&3)+8*(r>>2)+4*g32
#pragma unroll
    for (int mi = 0; mi < 4; ++mi) {
#pragma unroll
        for (int nh = 0; nh < 2; ++nh) {
#pragma unroll
            for (int r = 0; r < 16; ++r) {
                const int row = mBase + wm * 128 + mi * 32 + (r & 3) + 8 * (r >> 2) + 4 * g32;
                const int col = nBase + wn * 64 + nh * 32 + l31;
                C[(size_t)row * DIM_N + col] = acc[mi][nh][r];
            }
        }
    }
}

// ---------------------------------------------------------------------------
// Fallback (only if workspace too small): direct fp32, one thread per output
// ---------------------------------------------------------------------------
__global__ __launch_bounds__(256) void naive_kernel(
        const float* __restrict__ x, const float* __restrict__ alphas,
        const int* __restrict__ bases, float* __restrict__ out) {
    const long o = (long)blockIdx.x * 256 + threadIdx.x;
    const int m = (int)(o >> 12), n = (int)(o & 4095);
    const float a0 = alphas[0], a1 = alphas[1], a2 = alphas[2], a3 = alphas[3];
    const float* xr = x + (long)m * DIM_K;
    const int* b0 = bases + (long)n * DIM_K;
    const int* b1 = b0 + BASE_STRIDE;
    const int* b2 = b1 + BASE_STRIDE;
    const int* b3 = b2 + BASE_STRIDE;
    float acc = 0.f;
    for (int i = 0; i < DIM_K; i++) {
        float w = a0 * b0[i] + a1 * b1[i] + a2 * b2[i] + a3 * b3[i];
        acc += xr[i] * w;
    }
    out[o] = acc;
}

extern "C" void kernel_launch(void* const* d_in, const int* in_sizes, int n_in,
                              void* d_out, int out_size, void* d_ws, size_t ws_size,
                              hipStream_t stream) {
    const float* x      = (const float*)d_in[0];
    const float* alphas = (const float*)d_in[1];
    const int*   bases  = (const int*)d_in[2];
    float* out = (float*)d_out;

    const size_t need = (size_t)2 * DIM_N * DIM_K + (size_t)2 * DIM_M * DIM_K; // 64 MB
    if (ws_size >= need) {
        unsigned short* Wb = (unsigned short*)d_ws;                    // [4096][4096] bf16
        unsigned short* Xb = (unsigned short*)d_ws + (size_t)DIM_N * DIM_K;
        prep_kernel<<<16384, 256, 0, stream>>>(bases, alphas, x, Wb, Xb);
        gemm_bt_kernel<<<dim3(DIM_N / 256, DIM_M / 256), 512, 0, stream>>>(Xb, Wb, out);
    } else {
        naive_kernel<<<(DIM_M * DIM_N) / 256, 256, 0, stream>>>(x, alphas, bases, out);
    }
}